// Round 2
// baseline (142.143 us; speedup 1.0000x reference)
//
#include <hip/hip_runtime.h>

#define N_WORDS   16384
#define L_CHARS   16
#define CHAR_SIZE 128
#define C_EMB     64
#define CONV_L    256
#define KERNEL_K  3
#define D_EMB     300
#define OUT_STRIDE (CONV_L + D_EMB)   // 556
#define CH_Q      64                  // channels per quarter-slice
#define SLICE_H   (CHAR_SIZE * KERNEL_K * CH_Q)   // 24576 halves = 48 KB
#define WROW      (C_EMB * KERNEL_K)  // 192 floats per conv_w output row

typedef _Float16 half8 __attribute__((ext_vector_type(8)));
typedef _Float16 half4 __attribute__((ext_vector_type(4)));
typedef float    f32x4 __attribute__((ext_vector_type(4)));

static __device__ __forceinline__ half8 h8max(half8 a, half8 b) {
#if __has_builtin(__builtin_elementwise_max)
    return __builtin_elementwise_max(a, b);
#else
    half8 r;
    #pragma unroll
    for (int i = 0; i < 8; ++i) r[i] = a[i] > b[i] ? a[i] : b[i];
    return r;
#endif
}

// ---------------------------------------------------------------------------
// R4: SINGLE kernel. Char blocks fold their own 48 KB table slice in-block
// via MFMA (no build kernel, no global Th, no staging read, no sync).
//
//   Ts[c][kk] = sum_i emb[c][i] * w[q*64+(kk&63)][i][kk>>6],  kk = k*64+oi
//
// computed as C'[kk][c] = A'(kk,i) x B'(i,c), 16x16x32_f16 MFMA:
//   - A' = w-slice fragments (scalar stride-12B loads, L1/L2 resident;
//     each XCD serves one q: q=cb&3, XCD=cb%8)
//   - B' = emb fragments (contiguous float4 loads)
//   - both A and B use the SAME K-index formula (lane>>4)*8+e, so any
//     K-mapping uncertainty cancels in the contraction; C/D mapping is the
//     HW-verified col=lane&15, row=(lane>>4)*4+r.
//   - hi/lo double-split (hh+hl+lh MFMAs) reproduces fp32-product accuracy
//     -> table matches the old fp32 fold to <1 fp16 ulp.
//   - D regs are 4 consecutive kk -> packed ds_write_b64 at an XOR-swizzled
//     address: byte = c*384 + (kk_byte ^ ((c&7)<<4)). Conv reads apply the
//     same XOR (slot permutation per group; bank coverage identical to the
//     linear layout).
// Word blocks: gather only (2 independent HBM chains), unchanged.
// ---------------------------------------------------------------------------
__global__ __launch_bounds__(256, 3)
void main_kernel(const int* __restrict__ X,
                 const int* __restrict__ Xw,
                 const float* __restrict__ emb,
                 const float* __restrict__ w,
                 const float* __restrict__ conv_b,
                 const float* __restrict__ word_emb,
                 float* __restrict__ out,
                 int word_blocks) {
    __shared__ __align__(16) _Float16 Ts[SLICE_H];   // 48 KB

    const int lane = threadIdx.x & 63;
    const int wv   = threadIdx.x >> 6;

    if ((int)blockIdx.x < word_blocks) {
        const int wavesTotal = word_blocks * 4;          // 1024
        const int waveId = blockIdx.x * 4 + wv;
        for (int n = waveId; n < N_WORDS; n += 2 * wavesTotal) {
            const int n2 = n + wavesTotal;
            int w0 = Xw[n];
            int w1 = Xw[n2];
            const float4* s0 = (const float4*)(word_emb + (size_t)w0 * D_EMB);
            const float4* s1 = (const float4*)(word_emb + (size_t)w1 * D_EMB);
            const bool tail = lane < (D_EMB / 4 - 64);   // 11 lanes
            float4 a0 = s0[lane], a1 = s1[lane];
            float4 b0 = {}, b1 = {};
            if (tail) { b0 = s0[64 + lane]; b1 = s1[64 + lane]; }
            float4* d0 = (float4*)(out + (size_t)n  * OUT_STRIDE + CONV_L);
            float4* d1 = (float4*)(out + (size_t)n2 * OUT_STRIDE + CONV_L);
            d0[lane] = a0;
            if (tail) d0[64 + lane] = b0;
            d1[lane] = a1;
            if (tail) d1[64 + lane] = b1;
        }
        return;
    }

    const int cb   = (int)blockIdx.x - word_blocks;   // 0..511
    const int q    = cb & 3;                          // channel quarter
    const int wgrp = cb >> 2;                         // word group, 0..127

    // ================= in-block MFMA fold: build Ts =================
    {
        const int l15 = lane & 15;
        const int lg  = lane >> 4;
        const float* wq = w + (size_t)(q * CH_Q) * WROW;   // 64 o-rows, 48 KB

        #pragma unroll
        for (int ch = 0; ch < 2; ++ch) {          // c tiles [ch*64, ch*64+64)
            f32x4 acc[3][4];
            #pragma unroll
            for (int a = 0; a < 3; ++a)
                #pragma unroll
                for (int b = 0; b < 4; ++b) acc[a][b] = (f32x4)0.f;

            #pragma unroll
            for (int kc = 0; kc < 2; ++kc) {      // i chunks of 32
                // B' = emb fragments for 4 c-tiles (hi+lo)
                half8 Bh[4], Bl[4];
                #pragma unroll
                for (int ctl = 0; ctl < 4; ++ctl) {
                    const int c = (ch * 4 + ctl) * 16 + l15;
                    const float* ep = emb + c * C_EMB + kc * 32 + lg * 8;
                    float4 v0 = *(const float4*)ep;
                    float4 v1 = *(const float4*)(ep + 4);
                    float vv[8] = {v0.x, v0.y, v0.z, v0.w,
                                   v1.x, v1.y, v1.z, v1.w};
                    #pragma unroll
                    for (int e = 0; e < 8; ++e) {
                        _Float16 hi = (_Float16)vv[e];
                        Bh[ctl][e] = hi;
                        Bl[ctl][e] = (_Float16)(vv[e] - (float)hi);
                    }
                }
                // A' = w fragments, 3 kk-tiles owned by this wave
                #pragma unroll
                for (int mt = 0; mt < 3; ++mt) {
                    const int kk   = (wv * 3 + mt) * 16 + l15;
                    const int oi   = kk & 63;
                    const int kpos = kk >> 6;
                    const float* ap = wq + oi * WROW + kpos
                                      + (kc * 32 + lg * 8) * KERNEL_K;
                    half8 Ah, Al;
                    #pragma unroll
                    for (int e = 0; e < 8; ++e) {
                        float v = ap[e * KERNEL_K];
                        _Float16 hi = (_Float16)v;
                        Ah[e] = hi;
                        Al[e] = (_Float16)(v - (float)hi);
                    }
                    #pragma unroll
                    for (int ctl = 0; ctl < 4; ++ctl) {
                        acc[mt][ctl] = __builtin_amdgcn_mfma_f32_16x16x32_f16(
                            Ah, Bh[ctl], acc[mt][ctl], 0, 0, 0);
                        acc[mt][ctl] = __builtin_amdgcn_mfma_f32_16x16x32_f16(
                            Ah, Bl[ctl], acc[mt][ctl], 0, 0, 0);
                        acc[mt][ctl] = __builtin_amdgcn_mfma_f32_16x16x32_f16(
                            Al, Bh[ctl], acc[mt][ctl], 0, 0, 0);
                    }
                }
            }
            // write back: lane's 4 D-regs = 4 consecutive kk -> ds_write_b64
            #pragma unroll
            for (int mt = 0; mt < 3; ++mt) {
                #pragma unroll
                for (int ctl = 0; ctl < 4; ++ctl) {
                    const int kk0 = (wv * 3 + mt) * 16 + lg * 4;
                    const int c   = (ch * 4 + ctl) * 16 + l15;
                    half4 pk;
                    #pragma unroll
                    for (int r = 0; r < 4; ++r)
                        pk[r] = (_Float16)acc[mt][ctl][r];
                    const int byte = c * 384 + ((kk0 * 2) ^ ((c & 7) << 4));
                    *(half4*)((char*)Ts + byte) = pk;
                }
            }
        }
    }
    __syncthreads();

    // ================= conv / maxpool (swizzled reads) =================
    const int g  = lane >> 3;   // word within the wave's 8
    const int l8 = lane & 7;    // owns channels q*64 + l8*8 .. +8

    float bias[8];
    {
        const float4* bp = (const float4*)(conv_b + q * CH_Q + l8 * 8);
        float4 b0 = bp[0], b1 = bp[1];
        bias[0]=b0.x; bias[1]=b0.y; bias[2]=b0.z; bias[3]=b0.w;
        bias[4]=b1.x; bias[5]=b1.y; bias[6]=b1.z; bias[7]=b1.w;
    }

    // prefetch pass-0 X row (8 lanes share the 64 B row; L1 broadcast)
    int4 c0, c1, c2, c3;
    {
        const int n0 = wgrp * 128 + wv * 8 + g;
        const int4* xr = (const int4*)(X + n0 * L_CHARS);
        c0 = xr[0]; c1 = xr[1]; c2 = xr[2]; c3 = xr[3];
    }

    #pragma unroll
    for (int pass = 0; pass < 4; ++pass) {
        int4 p0 = c0, p1 = c1, p2 = c2, p3 = c3;
        if (pass < 3) {
            const int n1 = wgrp * 128 + (pass + 1) * 32 + wv * 8 + g;
            const int4* xr = (const int4*)(X + n1 * L_CHARS);
            p0 = xr[0]; p1 = xr[1]; p2 = xr[2]; p3 = xr[3];
        }

        const int n = wgrp * 128 + pass * 32 + wv * 8 + g;
        int cs[16] = {c0.x, c0.y, c0.z, c0.w,
                      c1.x, c1.y, c1.z, c1.w,
                      c2.x, c2.y, c2.z, c2.w,
                      c3.x, c3.y, c3.z, c3.w};

        half8 a0 = (half8)(_Float16)0.f;
        half8 a1 = (half8)(_Float16)0.f;
        half8 m  = (half8)(_Float16)(-65504.f);

        #pragma unroll
        for (int j = 0; j < L_CHARS; ++j) {
            const int cc = cs[j];
            const _Float16* row = Ts + cc * 192 + ((l8 ^ (cc & 7)) << 3);
            half8 t0 = *(const half8*)(row);            // k=0
            half8 t1 = *(const half8*)(row + 64);       // k=1
            half8 t2 = *(const half8*)(row + 128);      // k=2
            half8 yj = a0 + t2;          // y[j] complete
            m  = h8max(m, yj);
            a0 = a1 + t1;                // partial y[j+1]
            a1 = t0;                     // partial y[j+2]
        }
        m = h8max(m, a0);   // y[16]
        m = h8max(m, a1);   // y[17]

        float r[8];
        #pragma unroll
        for (int e = 0; e < 8; ++e)
            r[e] = fmaxf((float)m[e] + bias[e], 0.f);
        float4* dst = (float4*)(out + (size_t)n * OUT_STRIDE + q * CH_Q + l8 * 8);
        dst[0] = make_float4(r[0], r[1], r[2], r[3]);
        dst[1] = make_float4(r[4], r[5], r[6], r[7]);

        c0 = p0; c1 = p1; c2 = p2; c3 = p3;
    }
}

extern "C" void kernel_launch(void* const* d_in, const int* in_sizes, int n_in,
                              void* d_out, int out_size, void* d_ws, size_t ws_size,
                              hipStream_t stream) {
    const int*   X    = (const int*)d_in[0];
    const int*   Xw   = (const int*)d_in[1];
    const float* emb  = (const float*)d_in[2];
    const float* w    = (const float*)d_in[3];
    const float* b    = (const float*)d_in[4];
    const float* we   = (const float*)d_in[5];
    float* out = (float*)d_out;
    (void)d_ws; (void)ws_size;   // workspace no longer needed

    const int WB = 256;    // word-gather blocks
    const int CB = 512;    // char blocks: 4 quarters x 128 word-groups
    main_kernel<<<WB + CB, 256, 0, stream>>>(X, Xw, emb, w, b, we, out, WB);
}

// Round 3
// 127.092 us; speedup vs baseline: 1.1184x; 1.1184x over previous
//
#include <hip/hip_runtime.h>

#define N_WORDS   16384
#define L_CHARS   16
#define CHAR_SIZE 128
#define C_EMB     64
#define CONV_L    256
#define KERNEL_K  3
#define D_EMB     300
#define OUT_STRIDE (CONV_L + D_EMB)   // 556
#define CH_Q      64                  // channels per quarter-slice
#define SLICE_H   (CHAR_SIZE * KERNEL_K * CH_Q)   // 24576 halves = 48 KB
#define WROW      (C_EMB * KERNEL_K)  // 192 floats per conv_w output row
#define WPAD      196                 // padded LDS row stride (dwords): 2-way banks
#define LDS_BYTES (CH_Q * WPAD * 4)   // 50176 B; 3 blocks/CU = 150.5 KB <= 160

typedef _Float16 half8 __attribute__((ext_vector_type(8)));
typedef _Float16 half4 __attribute__((ext_vector_type(4)));
typedef float    f32x4 __attribute__((ext_vector_type(4)));

static __device__ __forceinline__ half8 h8max(half8 a, half8 b) {
#if __has_builtin(__builtin_elementwise_max)
    return __builtin_elementwise_max(a, b);
#else
    half8 r;
    #pragma unroll
    for (int i = 0; i < 8; ++i) r[i] = a[i] > b[i] ? a[i] : b[i];
    return r;
#endif
}

// ---------------------------------------------------------------------------
// R5: SINGLE kernel, cheap in-block fold (fixes R2's latency-bound fold).
//   1. stage w q-slice (48 KB) into LDS *coalesced* (float4), rows padded to
//      196 dwords -> fragment ds_reads are 2-way bank-aliased (free, m136).
//      [R2 read these as per-lane scalar global stride-12B loads: ~10^7 L2
//       line-requests -> the measured 49 us latency-bound kernel.]
//   2. extract A-fragments (w, hi/lo split) into 48 regs; __syncthreads.
//   3. MFMA fold (hh+hl+lh) BIT-IDENTICAL to R2's passing run, writing Ts
//      over the same LDS with R2's proven swizzled write/read pair:
//        write byte = c*384 + ((kk*2) ^ ((c&7)<<4))
//        read  byte = c*384 + k*128 + ((l8 ^ (c&7))<<4)
//   4. conv/maxpool identical to R1/R2.
// No build kernel, no Th global round-trip, no launch gap.
// Word blocks: gather only (2 independent HBM chains), unchanged from R1.
// ---------------------------------------------------------------------------
__global__ __launch_bounds__(256, 3)
void main_kernel(const int* __restrict__ X,
                 const int* __restrict__ Xw,
                 const float* __restrict__ emb,
                 const float* __restrict__ w,
                 const float* __restrict__ conv_b,
                 const float* __restrict__ word_emb,
                 float* __restrict__ out,
                 int word_blocks) {
    __shared__ __align__(16) char smem[LDS_BYTES];
    _Float16* Ts = (_Float16*)smem;   // 48 KB table, [c][k][oi] (swizzled)
    float*    Ws = (float*)smem;      // fold scratch: w rows padded to WPAD

    const int lane = threadIdx.x & 63;
    const int wv   = threadIdx.x >> 6;

    if ((int)blockIdx.x < word_blocks) {
        const int wavesTotal = word_blocks * 4;          // 1024
        const int waveId = blockIdx.x * 4 + wv;
        for (int n = waveId; n < N_WORDS; n += 2 * wavesTotal) {
            const int n2 = n + wavesTotal;
            int w0 = Xw[n];
            int w1 = Xw[n2];
            const float4* s0 = (const float4*)(word_emb + (size_t)w0 * D_EMB);
            const float4* s1 = (const float4*)(word_emb + (size_t)w1 * D_EMB);
            const bool tail = lane < (D_EMB / 4 - 64);   // 11 lanes
            float4 a0 = s0[lane], a1 = s1[lane];
            float4 b0 = {}, b1 = {};
            if (tail) { b0 = s0[64 + lane]; b1 = s1[64 + lane]; }
            float4* d0 = (float4*)(out + (size_t)n  * OUT_STRIDE + CONV_L);
            float4* d1 = (float4*)(out + (size_t)n2 * OUT_STRIDE + CONV_L);
            d0[lane] = a0;
            if (tail) d0[64 + lane] = b0;
            d1[lane] = a1;
            if (tail) d1[64 + lane] = b1;
        }
        return;
    }

    const int cb   = (int)blockIdx.x - word_blocks;   // 0..511
    const int q    = cb & 3;                          // channel quarter
    const int wgrp = cb >> 2;                         // word group, 0..127

    // ---- 1. stage w q-slice into padded LDS, fully coalesced ----
    {
        const float4* src = (const float4*)(w + (size_t)q * (CH_Q * WROW));
        #pragma unroll
        for (int i = 0; i < 12; ++i) {
            int f4  = threadIdx.x + i * 256;   // 0..3071
            int dw  = f4 * 4;
            int row = dw / WROW;               // magic-div, cheap
            int col = dw - row * WROW;         // multiple of 4
            *(float4*)(Ws + row * WPAD + col) = src[f4];
        }
    }
    __syncthreads();

    // ---- 2. A-fragments (w): 3 kk-tiles x 2 kc, hi/lo split ----
    const int l15 = lane & 15;
    const int lg  = lane >> 4;
    half8 Ah[3][2], Al[3][2];
    #pragma unroll
    for (int mt = 0; mt < 3; ++mt) {
        const int kk   = (wv * 3 + mt) * 16 + l15;
        const int oi   = kk & 63;
        const int kpos = kk >> 6;
        #pragma unroll
        for (int kc = 0; kc < 2; ++kc) {
            const float* ap = Ws + oi * WPAD + (kc * 32 + lg * 8) * KERNEL_K + kpos;
            #pragma unroll
            for (int e = 0; e < 8; ++e) {
                float v = ap[e * KERNEL_K];
                _Float16 hi = (_Float16)v;
                Ah[mt][kc][e] = hi;
                Al[mt][kc][e] = (_Float16)(v - (float)hi);
            }
        }
    }
    __syncthreads();   // all waves done reading Ws; Ts writes may begin

    // ---- 3. MFMA fold -> Ts (R2-proven math + swizzle pair) ----
    #pragma unroll
    for (int ch = 0; ch < 2; ++ch) {          // c tiles [ch*64, ch*64+64)
        f32x4 acc[3][4];
        #pragma unroll
        for (int a = 0; a < 3; ++a)
            #pragma unroll
            for (int b = 0; b < 4; ++b) acc[a][b] = (f32x4)0.f;

        #pragma unroll
        for (int kc = 0; kc < 2; ++kc) {      // i chunks of 32
            half8 Bh[4], Bl[4];
            #pragma unroll
            for (int ctl = 0; ctl < 4; ++ctl) {
                const int c = (ch * 4 + ctl) * 16 + l15;
                const float* ep = emb + c * C_EMB + kc * 32 + lg * 8;
                float4 v0 = *(const float4*)ep;
                float4 v1 = *(const float4*)(ep + 4);
                float vv[8] = {v0.x, v0.y, v0.z, v0.w,
                               v1.x, v1.y, v1.z, v1.w};
                #pragma unroll
                for (int e = 0; e < 8; ++e) {
                    _Float16 hi = (_Float16)vv[e];
                    Bh[ctl][e] = hi;
                    Bl[ctl][e] = (_Float16)(vv[e] - (float)hi);
                }
            }
            #pragma unroll
            for (int mt = 0; mt < 3; ++mt) {
                #pragma unroll
                for (int ctl = 0; ctl < 4; ++ctl) {
                    acc[mt][ctl] = __builtin_amdgcn_mfma_f32_16x16x32_f16(
                        Ah[mt][kc], Bh[ctl], acc[mt][ctl], 0, 0, 0);
                    acc[mt][ctl] = __builtin_amdgcn_mfma_f32_16x16x32_f16(
                        Ah[mt][kc], Bl[ctl], acc[mt][ctl], 0, 0, 0);
                    acc[mt][ctl] = __builtin_amdgcn_mfma_f32_16x16x32_f16(
                        Al[mt][kc], Bh[ctl], acc[mt][ctl], 0, 0, 0);
                }
            }
        }
        // write back: lane's 4 D-regs = 4 consecutive kk -> ds_write_b64,
        // XOR-swizzled (2-way banks instead of 16-way for linear).
        #pragma unroll
        for (int mt = 0; mt < 3; ++mt) {
            #pragma unroll
            for (int ctl = 0; ctl < 4; ++ctl) {
                const int kk0 = (wv * 3 + mt) * 16 + lg * 4;
                const int c   = (ch * 4 + ctl) * 16 + l15;
                half4 pk;
                #pragma unroll
                for (int r = 0; r < 4; ++r)
                    pk[r] = (_Float16)acc[mt][ctl][r];
                const int byte = c * 384 + ((kk0 * 2) ^ ((c & 7) << 4));
                *(half4*)((char*)Ts + byte) = pk;
            }
        }
    }
    __syncthreads();

    // ---- 4. conv / maxpool (swizzled reads, R2-proven) ----
    const int g  = lane >> 3;   // word within the wave's 8
    const int l8 = lane & 7;    // owns channels q*64 + l8*8 .. +8

    float bias[8];
    {
        const float4* bp = (const float4*)(conv_b + q * CH_Q + l8 * 8);
        float4 b0 = bp[0], b1 = bp[1];
        bias[0]=b0.x; bias[1]=b0.y; bias[2]=b0.z; bias[3]=b0.w;
        bias[4]=b1.x; bias[5]=b1.y; bias[6]=b1.z; bias[7]=b1.w;
    }

    // prefetch pass-0 X row (8 lanes share the 64 B row; L1 broadcast)
    int4 c0, c1, c2, c3;
    {
        const int n0 = wgrp * 128 + wv * 8 + g;
        const int4* xr = (const int4*)(X + n0 * L_CHARS);
        c0 = xr[0]; c1 = xr[1]; c2 = xr[2]; c3 = xr[3];
    }

    #pragma unroll
    for (int pass = 0; pass < 4; ++pass) {
        int4 p0 = c0, p1 = c1, p2 = c2, p3 = c3;
        if (pass < 3) {
            const int n1 = wgrp * 128 + (pass + 1) * 32 + wv * 8 + g;
            const int4* xr = (const int4*)(X + n1 * L_CHARS);
            p0 = xr[0]; p1 = xr[1]; p2 = xr[2]; p3 = xr[3];
        }

        const int n = wgrp * 128 + pass * 32 + wv * 8 + g;
        int cs[16] = {c0.x, c0.y, c0.z, c0.w,
                      c1.x, c1.y, c1.z, c1.w,
                      c2.x, c2.y, c2.z, c2.w,
                      c3.x, c3.y, c3.z, c3.w};

        half8 a0 = (half8)(_Float16)0.f;
        half8 a1 = (half8)(_Float16)0.f;
        half8 m  = (half8)(_Float16)(-65504.f);

        #pragma unroll
        for (int j = 0; j < L_CHARS; ++j) {
            const int cc = cs[j];
            const _Float16* row = Ts + cc * 192 + ((l8 ^ (cc & 7)) << 3);
            half8 t0 = *(const half8*)(row);            // k=0
            half8 t1 = *(const half8*)(row + 64);       // k=1
            half8 t2 = *(const half8*)(row + 128);      // k=2
            half8 yj = a0 + t2;          // y[j] complete
            m  = h8max(m, yj);
            a0 = a1 + t1;                // partial y[j+1]
            a1 = t0;                     // partial y[j+2]
        }
        m = h8max(m, a0);   // y[16]
        m = h8max(m, a1);   // y[17]

        float r[8];
        #pragma unroll
        for (int e = 0; e < 8; ++e)
            r[e] = fmaxf((float)m[e] + bias[e], 0.f);
        float4* dst = (float4*)(out + (size_t)n * OUT_STRIDE + q * CH_Q + l8 * 8);
        dst[0] = make_float4(r[0], r[1], r[2], r[3]);
        dst[1] = make_float4(r[4], r[5], r[6], r[7]);

        c0 = p0; c1 = p1; c2 = p2; c3 = p3;
    }
}

extern "C" void kernel_launch(void* const* d_in, const int* in_sizes, int n_in,
                              void* d_out, int out_size, void* d_ws, size_t ws_size,
                              hipStream_t stream) {
    const int*   X    = (const int*)d_in[0];
    const int*   Xw   = (const int*)d_in[1];
    const float* emb  = (const float*)d_in[2];
    const float* w    = (const float*)d_in[3];
    const float* b    = (const float*)d_in[4];
    const float* we   = (const float*)d_in[5];
    float* out = (float*)d_out;
    (void)d_ws; (void)ws_size;   // workspace not needed

    const int WB = 256;    // word-gather blocks
    const int CB = 512;    // char blocks: 4 quarters x 128 word-groups
    main_kernel<<<WB + CB, 256, 0, stream>>>(X, Xw, emb, w, b, we, out, WB);
}

// Round 4
// 124.305 us; speedup vs baseline: 1.1435x; 1.0224x over previous
//
#include <hip/hip_runtime.h>

#define N_WORDS   16384
#define L_CHARS   16
#define CHAR_SIZE 128
#define C_EMB     64
#define CONV_L    256
#define KERNEL_K  3
#define D_EMB     300
#define OUT_STRIDE (CONV_L + D_EMB)   // 556
#define CH_Q      64                  // channels per quarter-slice
#define SLICE_H   (CHAR_SIZE * KERNEL_K * CH_Q)   // 24576 halves = 48 KB
#define WROW      (C_EMB * KERNEL_K)  // 192 floats per conv_w output row
#define WPAD      196                 // padded LDS row stride (dwords)
#define LDS_BYTES (CH_Q * WPAD * 4)   // 50176 B; 3 blocks/CU = 150.5 KB <= 160

typedef _Float16 half8 __attribute__((ext_vector_type(8)));
typedef _Float16 half4 __attribute__((ext_vector_type(4)));
typedef float    f32x4 __attribute__((ext_vector_type(4)));

static __device__ __forceinline__ half8 h8max(half8 a, half8 b) {
#if __has_builtin(__builtin_elementwise_max)
    return __builtin_elementwise_max(a, b);
#else
    half8 r;
    #pragma unroll
    for (int i = 0; i < 8; ++i) r[i] = a[i] > b[i] ? a[i] : b[i];
    return r;
#endif
}

// ---------------------------------------------------------------------------
// R6: single kernel; SLIM in-block fold (fixes R3's 16 us fold).
// Model from R0-R3: dur = 83 (fills) + ~10/kernel-node + kernel time.
// R3's fold was VGPR-bound (A hi/lo + B hi/lo + acc > 170 cap -> spills).
// Changes vs R3 (conv + gather + swizzle pair byte-identical, proven):
//   - A-side lo term dropped: acc += Ah*Bh + Ah*Bl  (2 MFMAs/tile, 96 total)
//     error added: std ~1.4e-4 table-entry, 15x below the conv-fp16-dominated
//     absmax 0.015625. A-extract halves to 48 scalar ds_reads/lane.
//   - peak live ~120 VGPR: acc 48 + B 32 + A 24 + misc -> no spill at the
//     (256,3) 170 cap; 3 blocks/CU (LDS 50176*3 = 150.5 KB) preserved.
//   - pass-0 X rows + bias prefetched BEFORE the fold (latency hides under
//     the 96 MFMAs + B-split VALU).
// ---------------------------------------------------------------------------
__global__ __launch_bounds__(256, 3)
void main_kernel(const int* __restrict__ X,
                 const int* __restrict__ Xw,
                 const float* __restrict__ emb,
                 const float* __restrict__ w,
                 const float* __restrict__ conv_b,
                 const float* __restrict__ word_emb,
                 float* __restrict__ out,
                 int word_blocks) {
    __shared__ __align__(16) char smem[LDS_BYTES];
    _Float16* Ts = (_Float16*)smem;   // 48 KB table, [c][k][oi] (swizzled)
    float*    Ws = (float*)smem;      // fold scratch: w rows padded to WPAD

    const int lane = threadIdx.x & 63;
    const int wv   = threadIdx.x >> 6;

    if ((int)blockIdx.x < word_blocks) {
        const int wavesTotal = word_blocks * 4;          // 1024
        const int waveId = blockIdx.x * 4 + wv;
        for (int n = waveId; n < N_WORDS; n += 2 * wavesTotal) {
            const int n2 = n + wavesTotal;
            int w0 = Xw[n];
            int w1 = Xw[n2];
            const float4* s0 = (const float4*)(word_emb + (size_t)w0 * D_EMB);
            const float4* s1 = (const float4*)(word_emb + (size_t)w1 * D_EMB);
            const bool tail = lane < (D_EMB / 4 - 64);   // 11 lanes
            float4 a0 = s0[lane], a1 = s1[lane];
            float4 b0 = {}, b1 = {};
            if (tail) { b0 = s0[64 + lane]; b1 = s1[64 + lane]; }
            float4* d0 = (float4*)(out + (size_t)n  * OUT_STRIDE + CONV_L);
            float4* d1 = (float4*)(out + (size_t)n2 * OUT_STRIDE + CONV_L);
            d0[lane] = a0;
            if (tail) d0[64 + lane] = b0;
            d1[lane] = a1;
            if (tail) d1[64 + lane] = b1;
        }
        return;
    }

    const int cb   = (int)blockIdx.x - word_blocks;   // 0..511
    const int q    = cb & 3;                          // channel quarter
    const int wgrp = cb >> 2;                         // word group, 0..127

    // ---- 1. stage w q-slice into padded LDS, fully coalesced ----
    {
        const float4* src = (const float4*)(w + (size_t)q * (CH_Q * WROW));
        #pragma unroll
        for (int i = 0; i < 12; ++i) {
            int f4  = threadIdx.x + i * 256;   // 0..3071
            int dw  = f4 * 4;
            int row = dw / WROW;               // magic-div, cheap
            int col = dw - row * WROW;         // multiple of 4
            *(float4*)(Ws + row * WPAD + col) = src[f4];
        }
    }
    __syncthreads();

    // ---- 2. A-fragments (w, single-rounded fp16): 3 kk-tiles x 2 kc ----
    const int l15 = lane & 15;
    const int lg  = lane >> 4;
    half8 Ah[3][2];
    #pragma unroll
    for (int mt = 0; mt < 3; ++mt) {
        const int kk   = (wv * 3 + mt) * 16 + l15;
        const int oi   = kk & 63;
        const int kpos = kk >> 6;
        #pragma unroll
        for (int kc = 0; kc < 2; ++kc) {
            const float* ap = Ws + oi * WPAD + (kc * 32 + lg * 8) * KERNEL_K + kpos;
            #pragma unroll
            for (int e = 0; e < 8; ++e)
                Ah[mt][kc][e] = (_Float16)ap[e * KERNEL_K];
        }
    }
    __syncthreads();   // all waves done reading Ws; Ts writes may begin

    // ---- prefetch pass-0 X rows + bias: latency hides under the fold ----
    const int g  = lane >> 3;   // word within the wave's 8
    const int l8 = lane & 7;    // owns channels q*64 + l8*8 .. +8
    int4 c0, c1, c2, c3;
    {
        const int n0 = wgrp * 128 + wv * 8 + g;
        const int4* xr = (const int4*)(X + n0 * L_CHARS);
        c0 = xr[0]; c1 = xr[1]; c2 = xr[2]; c3 = xr[3];
    }
    float bias[8];
    {
        const float4* bp = (const float4*)(conv_b + q * CH_Q + l8 * 8);
        float4 b0 = bp[0], b1 = bp[1];
        bias[0]=b0.x; bias[1]=b0.y; bias[2]=b0.z; bias[3]=b0.w;
        bias[4]=b1.x; bias[5]=b1.y; bias[6]=b1.z; bias[7]=b1.w;
    }

    // ---- 3. MFMA fold -> Ts (Ah*Bh + Ah*Bl; swizzle pair R2/R3-proven) ----
    #pragma unroll
    for (int ch = 0; ch < 2; ++ch) {          // c tiles [ch*64, ch*64+64)
        f32x4 acc[3][4];
        #pragma unroll
        for (int a = 0; a < 3; ++a)
            #pragma unroll
            for (int b = 0; b < 4; ++b) acc[a][b] = (f32x4)0.f;

        #pragma unroll
        for (int kc = 0; kc < 2; ++kc) {      // i chunks of 32
            half8 Bh[4], Bl[4];
            #pragma unroll
            for (int ctl = 0; ctl < 4; ++ctl) {
                const int c = (ch * 4 + ctl) * 16 + l15;
                const float* ep = emb + c * C_EMB + kc * 32 + lg * 8;
                float4 v0 = *(const float4*)ep;
                float4 v1 = *(const float4*)(ep + 4);
                float vv[8] = {v0.x, v0.y, v0.z, v0.w,
                               v1.x, v1.y, v1.z, v1.w};
                #pragma unroll
                for (int e = 0; e < 8; ++e) {
                    _Float16 hi = (_Float16)vv[e];
                    Bh[ctl][e] = hi;
                    Bl[ctl][e] = (_Float16)(vv[e] - (float)hi);
                }
            }
            #pragma unroll
            for (int mt = 0; mt < 3; ++mt) {
                #pragma unroll
                for (int ctl = 0; ctl < 4; ++ctl) {
                    acc[mt][ctl] = __builtin_amdgcn_mfma_f32_16x16x32_f16(
                        Ah[mt][kc], Bh[ctl], acc[mt][ctl], 0, 0, 0);
                    acc[mt][ctl] = __builtin_amdgcn_mfma_f32_16x16x32_f16(
                        Ah[mt][kc], Bl[ctl], acc[mt][ctl], 0, 0, 0);
                }
            }
        }
        // write back: lane's 4 D-regs = 4 consecutive kk -> ds_write_b64
        #pragma unroll
        for (int mt = 0; mt < 3; ++mt) {
            #pragma unroll
            for (int ctl = 0; ctl < 4; ++ctl) {
                const int kk0 = (wv * 3 + mt) * 16 + lg * 4;
                const int c   = (ch * 4 + ctl) * 16 + l15;
                half4 pk;
                #pragma unroll
                for (int r = 0; r < 4; ++r)
                    pk[r] = (_Float16)acc[mt][ctl][r];
                const int byte = c * 384 + ((kk0 * 2) ^ ((c & 7) << 4));
                *(half4*)((char*)Ts + byte) = pk;
            }
        }
    }
    __syncthreads();

    // ---- 4. conv / maxpool (swizzled reads, byte-identical to R3) ----
    #pragma unroll
    for (int pass = 0; pass < 4; ++pass) {
        int4 p0 = c0, p1 = c1, p2 = c2, p3 = c3;
        if (pass < 3) {
            const int n1 = wgrp * 128 + (pass + 1) * 32 + wv * 8 + g;
            const int4* xr = (const int4*)(X + n1 * L_CHARS);
            p0 = xr[0]; p1 = xr[1]; p2 = xr[2]; p3 = xr[3];
        }

        const int n = wgrp * 128 + pass * 32 + wv * 8 + g;
        int cs[16] = {c0.x, c0.y, c0.z, c0.w,
                      c1.x, c1.y, c1.z, c1.w,
                      c2.x, c2.y, c2.z, c2.w,
                      c3.x, c3.y, c3.z, c3.w};

        half8 a0 = (half8)(_Float16)0.f;
        half8 a1 = (half8)(_Float16)0.f;
        half8 m  = (half8)(_Float16)(-65504.f);

        #pragma unroll
        for (int j = 0; j < L_CHARS; ++j) {
            const int cc = cs[j];
            const _Float16* row = Ts + cc * 192 + ((l8 ^ (cc & 7)) << 3);
            half8 t0 = *(const half8*)(row);            // k=0
            half8 t1 = *(const half8*)(row + 64);       // k=1
            half8 t2 = *(const half8*)(row + 128);      // k=2
            half8 yj = a0 + t2;          // y[j] complete
            m  = h8max(m, yj);
            a0 = a1 + t1;                // partial y[j+1]
            a1 = t0;                     // partial y[j+2]
        }
        m = h8max(m, a0);   // y[16]
        m = h8max(m, a1);   // y[17]

        float r[8];
        #pragma unroll
        for (int e = 0; e < 8; ++e)
            r[e] = fmaxf((float)m[e] + bias[e], 0.f);
        float4* dst = (float4*)(out + (size_t)n * OUT_STRIDE + q * CH_Q + l8 * 8);
        dst[0] = make_float4(r[0], r[1], r[2], r[3]);
        dst[1] = make_float4(r[4], r[5], r[6], r[7]);

        c0 = p0; c1 = p1; c2 = p2; c3 = p3;
    }
}

extern "C" void kernel_launch(void* const* d_in, const int* in_sizes, int n_in,
                              void* d_out, int out_size, void* d_ws, size_t ws_size,
                              hipStream_t stream) {
    const int*   X    = (const int*)d_in[0];
    const int*   Xw   = (const int*)d_in[1];
    const float* emb  = (const float*)d_in[2];
    const float* w    = (const float*)d_in[3];
    const float* b    = (const float*)d_in[4];
    const float* we   = (const float*)d_in[5];
    float* out = (float*)d_out;
    (void)d_ws; (void)ws_size;   // workspace not needed

    const int WB = 256;    // word-gather blocks
    const int CB = 512;    // char blocks: 4 quarters x 128 word-groups
    main_kernel<<<WB + CB, 256, 0, stream>>>(X, Xw, emb, w, b, we, out, WB);
}

// Round 5
// 119.914 us; speedup vs baseline: 1.1854x; 1.0366x over previous
//
#include <hip/hip_runtime.h>

#define N_WORDS   16384
#define L_CHARS   16
#define CHAR_SIZE 128
#define C_EMB     64
#define CONV_L    256
#define KERNEL_K  3
#define D_EMB     300
#define OUT_STRIDE (CONV_L + D_EMB)   // 556
#define CH_Q      64                  // channels per quarter-slice
#define SLICE_H   (CHAR_SIZE * KERNEL_K * CH_Q)   // 24576 halves = 48 KB

typedef _Float16 half8 __attribute__((ext_vector_type(8)));

static __device__ __forceinline__ half8 h8max(half8 a, half8 b) {
#if __has_builtin(__builtin_elementwise_max)
    return __builtin_elementwise_max(a, b);
#else
    half8 r;
    #pragma unroll
    for (int i = 0; i < 8; ++i) r[i] = a[i] > b[i] ? a[i] : b[i];
    return r;
#endif
}

// ---------------------------------------------------------------------------
// R7 = R1 structure (best measured: 123.5) + targeted latency fixes.
// Evidence: in-block fold costs +8-13 us at any register budget (R2/R3/R4
// differentials) -- 128x-redundant work on the critical path + 8-way-
// conflicted A-extract (R2's 1.94M conflict cycles). Amortized build kernel
// (~2.5 us) + launch gap wins. Conv-phase b128 LDS reads are provably even
// (8/bank floor), so the linear table layout stays.
//
// Kernel A (R1-proven, bit-identical): fused transpose+fold -> Th in ws.
__global__ __launch_bounds__(384)
void build_table_fused(const float* __restrict__ emb,
                       const float* __restrict__ w,
                       _Float16* __restrict__ Th) {
    __shared__ float es[CHAR_SIZE * 65];          // 33.3 KB, 2-way banks
    __shared__ float ws[C_EMB * KERNEL_K];        // 768 B
    const int o = blockIdx.x;

    for (int idx = threadIdx.x; idx < CHAR_SIZE * C_EMB; idx += 384) {
        int c = idx >> 6, i = idx & 63;
        es[c * 65 + i] = emb[idx];
    }
    if (threadIdx.x < C_EMB * KERNEL_K)
        ws[threadIdx.x] = w[o * (C_EMB * KERNEL_K) + threadIdx.x];
    __syncthreads();

    const int k = threadIdx.x >> 7;    // 0..2, uniform per 64-lane wave
    const int c = threadIdx.x & 127;
    float s = 0.f;
    #pragma unroll
    for (int i = 0; i < C_EMB; ++i)
        s += es[c * 65 + i] * ws[i * KERNEL_K + k];

    Th[(o >> 6) * SLICE_H + c * (KERNEL_K * CH_Q) + k * CH_Q + (o & 63)]
        = (_Float16)s;
}

// ---------------------------------------------------------------------------
// Kernel B (fused main).
// Word blocks: gather with 4 INDEPENDENT chains (R7: was 2) -> 4 rounds of
//   4 parallel row-gathers instead of 8 rounds of 2; halves exposed HBM
//   latency, BW unchanged.
// Char blocks: X-row + bias loads hoisted BEFORE the 48 KB staging loop --
//   their latency drains under the staging vmcnt, not after the barrier.
//   Conv j-loop / linear table / CB=512 byte-identical to R1 (proven).
__global__ __launch_bounds__(256, 3)
void main_kernel(const int* __restrict__ X,
                 const int* __restrict__ Xw,
                 const _Float16* __restrict__ Th,
                 const float* __restrict__ conv_b,
                 const float* __restrict__ word_emb,
                 float* __restrict__ out,
                 int word_blocks) {
    __shared__ __align__(16) _Float16 Ts[SLICE_H];   // 48 KB -> 3 blocks/CU

    const int lane = threadIdx.x & 63;
    const int wv   = threadIdx.x >> 6;

    if ((int)blockIdx.x < word_blocks) {
        const int wavesTotal = word_blocks * 4;          // 1024
        const int waveId = blockIdx.x * 4 + wv;
        // 16384 / (4*1024) = 4 rounds; all four chains always in bounds.
        for (int n = waveId; n < N_WORDS; n += 4 * wavesTotal) {
            const int n1 = n + wavesTotal;
            const int n2 = n + 2 * wavesTotal;
            const int n3 = n + 3 * wavesTotal;
            int w0 = Xw[n], w1 = Xw[n1], w2 = Xw[n2], w3 = Xw[n3];
            const float4* s0 = (const float4*)(word_emb + (size_t)w0 * D_EMB);
            const float4* s1 = (const float4*)(word_emb + (size_t)w1 * D_EMB);
            const float4* s2 = (const float4*)(word_emb + (size_t)w2 * D_EMB);
            const float4* s3 = (const float4*)(word_emb + (size_t)w3 * D_EMB);
            const bool tail = lane < (D_EMB / 4 - 64);   // 11 lanes
            float4 a0 = s0[lane], a1 = s1[lane], a2 = s2[lane], a3 = s3[lane];
            float4 b0 = {}, b1 = {}, b2 = {}, b3 = {};
            if (tail) {
                b0 = s0[64 + lane]; b1 = s1[64 + lane];
                b2 = s2[64 + lane]; b3 = s3[64 + lane];
            }
            float4* d0 = (float4*)(out + (size_t)n  * OUT_STRIDE + CONV_L);
            float4* d1 = (float4*)(out + (size_t)n1 * OUT_STRIDE + CONV_L);
            float4* d2 = (float4*)(out + (size_t)n2 * OUT_STRIDE + CONV_L);
            float4* d3 = (float4*)(out + (size_t)n3 * OUT_STRIDE + CONV_L);
            d0[lane] = a0;
            d1[lane] = a1;
            d2[lane] = a2;
            d3[lane] = a3;
            if (tail) {
                d0[64 + lane] = b0; d1[64 + lane] = b1;
                d2[64 + lane] = b2; d3[64 + lane] = b3;
            }
        }
        return;
    }

    const int cb   = (int)blockIdx.x - word_blocks;   // 0..511
    const int q    = cb & 3;                          // channel quarter
    const int wgrp = cb >> 2;                         // word group, 0..127

    const int g  = lane >> 3;   // word within the wave's 8
    const int l8 = lane & 7;    // owns channels q*64 + l8*8 .. +8

    // ---- hoisted global loads: X pass-0 row + bias (drain under staging) --
    int4 c0, c1, c2, c3;
    {
        const int n0 = wgrp * 128 + wv * 8 + g;
        const int4* xr = (const int4*)(X + n0 * L_CHARS);
        c0 = xr[0]; c1 = xr[1]; c2 = xr[2]; c3 = xr[3];
    }
    float bias[8];
    {
        const float4* bp = (const float4*)(conv_b + q * CH_Q + l8 * 8);
        float4 b0 = bp[0], b1 = bp[1];
        bias[0]=b0.x; bias[1]=b0.y; bias[2]=b0.z; bias[3]=b0.w;
        bias[4]=b1.x; bias[5]=b1.y; bias[6]=b1.z; bias[7]=b1.w;
    }

    // ---- stage the 48 KB slice (fully coalesced contiguous read) ----
    {
        const float4* src = (const float4*)(Th + q * SLICE_H);
        float4* dst = (float4*)Ts;
        #pragma unroll
        for (int i = 0; i < 12; ++i)
            dst[threadIdx.x + i * 256] = src[threadIdx.x + i * 256];
    }
    __syncthreads();

    #pragma unroll
    for (int pass = 0; pass < 4; ++pass) {
        int4 p0 = c0, p1 = c1, p2 = c2, p3 = c3;
        if (pass < 3) {
            const int n1 = wgrp * 128 + (pass + 1) * 32 + wv * 8 + g;
            const int4* xr = (const int4*)(X + n1 * L_CHARS);
            p0 = xr[0]; p1 = xr[1]; p2 = xr[2]; p3 = xr[3];
        }

        const int n = wgrp * 128 + pass * 32 + wv * 8 + g;
        int cs[16] = {c0.x, c0.y, c0.z, c0.w,
                      c1.x, c1.y, c1.z, c1.w,
                      c2.x, c2.y, c2.z, c2.w,
                      c3.x, c3.y, c3.z, c3.w};

        half8 a0 = (half8)(_Float16)0.f;
        half8 a1 = (half8)(_Float16)0.f;
        half8 m  = (half8)(_Float16)(-65504.f);

        #pragma unroll
        for (int j = 0; j < L_CHARS; ++j) {
            const _Float16* row = Ts + cs[j] * (KERNEL_K * CH_Q) + l8 * 8;
            half8 t0 = *(const half8*)(row);            // k=0
            half8 t1 = *(const half8*)(row + CH_Q);     // k=1
            half8 t2 = *(const half8*)(row + 2*CH_Q);   // k=2
            half8 yj = a0 + t2;          // y[j] complete
            m  = h8max(m, yj);
            a0 = a1 + t1;                // partial y[j+1]
            a1 = t0;                     // partial y[j+2]
        }
        m = h8max(m, a0);   // y[16]
        m = h8max(m, a1);   // y[17]

        float r[8];
        #pragma unroll
        for (int e = 0; e < 8; ++e)
            r[e] = fmaxf((float)m[e] + bias[e], 0.f);
        float4* dst = (float4*)(out + (size_t)n * OUT_STRIDE + q * CH_Q + l8 * 8);
        dst[0] = make_float4(r[0], r[1], r[2], r[3]);
        dst[1] = make_float4(r[4], r[5], r[6], r[7]);

        c0 = p0; c1 = p1; c2 = p2; c3 = p3;
    }
}

extern "C" void kernel_launch(void* const* d_in, const int* in_sizes, int n_in,
                              void* d_out, int out_size, void* d_ws, size_t ws_size,
                              hipStream_t stream) {
    const int*   X    = (const int*)d_in[0];
    const int*   Xw   = (const int*)d_in[1];
    const float* emb  = (const float*)d_in[2];
    const float* w    = (const float*)d_in[3];
    const float* b    = (const float*)d_in[4];
    const float* we   = (const float*)d_in[5];
    float* out = (float*)d_out;

    // ws layout: Th (fp16, 196608 B)
    _Float16* Th = (_Float16*)d_ws;

    build_table_fused<<<CONV_L, 384, 0, stream>>>(emb, w, Th);

    const int WB = 256;    // word-gather blocks
    const int CB = 512;    // char blocks: 4 quarters x 128 word-groups
    main_kernel<<<WB + CB, 256, 0, stream>>>(X, Xw, Th, b, we, out, WB);
}

// Round 7
// 119.249 us; speedup vs baseline: 1.1920x; 1.0056x over previous
//
#include <hip/hip_runtime.h>

#define N_WORDS   16384
#define L_CHARS   16
#define CHAR_SIZE 128
#define C_EMB     64
#define CONV_L    256
#define KERNEL_K  3
#define D_EMB     300
#define OUT_STRIDE (CONV_L + D_EMB)   // 556
#define CH_Q      64                  // channels per quarter-slice
#define SLICE_H   (CHAR_SIZE * KERNEL_K * CH_Q)   // 24576 halves = 48 KB

typedef _Float16 half8 __attribute__((ext_vector_type(8)));

static __device__ __forceinline__ half8 h8max(half8 a, half8 b) {
#if __has_builtin(__builtin_elementwise_max)
    return __builtin_elementwise_max(a, b);
#else
    half8 r;
    #pragma unroll
    for (int i = 0; i < 8; ++i) r[i] = a[i] > b[i] ? a[i] : b[i];
    return r;
#endif
}

// ---------------------------------------------------------------------------
// R9 = R5 restored verbatim (proven 119.9 us; best measured).
// Session evidence for this structure:
//   - in-block per-char-block fold: +8..13 us at any register budget
//     (R2=49.3, R3=34.3, R4=31.5 us main vs ~18 here) -- 128x-redundant
//     work on the critical path. Rejected.
//   - cross-block producer/consumer publish (R8): container failure --
//     dispatch-order-dependent sync is incompatible with graph capture +
//     rocprof replay (Guideline 16). Rejected.
//   - two-kernel amortized build (2.5 us) + launch boundary is the winner.
//
// Kernel A: fused transpose+fold -> Th in ws (bit-identical accumulation
// order across all passing rounds; absmax 0.015625 dominated by fp16 conv).
__global__ __launch_bounds__(384)
void build_table_fused(const float* __restrict__ emb,
                       const float* __restrict__ w,
                       _Float16* __restrict__ Th) {
    __shared__ float es[CHAR_SIZE * 65];          // 33.3 KB, 2-way banks
    __shared__ float ws[C_EMB * KERNEL_K];        // 768 B
    const int o = blockIdx.x;

    for (int idx = threadIdx.x; idx < CHAR_SIZE * C_EMB; idx += 384) {
        int c = idx >> 6, i = idx & 63;
        es[c * 65 + i] = emb[idx];
    }
    if (threadIdx.x < C_EMB * KERNEL_K)
        ws[threadIdx.x] = w[o * (C_EMB * KERNEL_K) + threadIdx.x];
    __syncthreads();

    const int k = threadIdx.x >> 7;    // 0..2, uniform per 64-lane wave
    const int c = threadIdx.x & 127;
    float s = 0.f;
    #pragma unroll
    for (int i = 0; i < C_EMB; ++i)
        s += es[c * 65 + i] * ws[i * KERNEL_K + k];

    Th[(o >> 6) * SLICE_H + c * (KERNEL_K * CH_Q) + k * CH_Q + (o & 63)]
        = (_Float16)s;
}

// ---------------------------------------------------------------------------
// Kernel B (fused main).
// Word blocks: gather with 4 independent chains -> 4 rounds of 4 parallel
//   row-gathers; halves exposed HBM latency vs 2-chain, BW unchanged.
// Char blocks: X-row + bias loads hoisted BEFORE the 48 KB staging loop --
//   their latency drains under the staging vmcnt, not after the barrier.
//   Conv j-loop / linear table / CB=512 proven across R1/R5.
__global__ __launch_bounds__(256, 3)
void main_kernel(const int* __restrict__ X,
                 const int* __restrict__ Xw,
                 const _Float16* __restrict__ Th,
                 const float* __restrict__ conv_b,
                 const float* __restrict__ word_emb,
                 float* __restrict__ out,
                 int word_blocks) {
    __shared__ __align__(16) _Float16 Ts[SLICE_H];   // 48 KB -> 3 blocks/CU

    const int lane = threadIdx.x & 63;
    const int wv   = threadIdx.x >> 6;

    if ((int)blockIdx.x < word_blocks) {
        const int wavesTotal = word_blocks * 4;          // 1024
        const int waveId = blockIdx.x * 4 + wv;
        // 16384 / (4*1024) = 4 rounds; all four chains always in bounds.
        for (int n = waveId; n < N_WORDS; n += 4 * wavesTotal) {
            const int n1 = n + wavesTotal;
            const int n2 = n + 2 * wavesTotal;
            const int n3 = n + 3 * wavesTotal;
            int w0 = Xw[n], w1 = Xw[n1], w2 = Xw[n2], w3 = Xw[n3];
            const float4* s0 = (const float4*)(word_emb + (size_t)w0 * D_EMB);
            const float4* s1 = (const float4*)(word_emb + (size_t)w1 * D_EMB);
            const float4* s2 = (const float4*)(word_emb + (size_t)w2 * D_EMB);
            const float4* s3 = (const float4*)(word_emb + (size_t)w3 * D_EMB);
            const bool tail = lane < (D_EMB / 4 - 64);   // 11 lanes
            float4 a0 = s0[lane], a1 = s1[lane], a2 = s2[lane], a3 = s3[lane];
            float4 b0 = {}, b1 = {}, b2 = {}, b3 = {};
            if (tail) {
                b0 = s0[64 + lane]; b1 = s1[64 + lane];
                b2 = s2[64 + lane]; b3 = s3[64 + lane];
            }
            float4* d0 = (float4*)(out + (size_t)n  * OUT_STRIDE + CONV_L);
            float4* d1 = (float4*)(out + (size_t)n1 * OUT_STRIDE + CONV_L);
            float4* d2 = (float4*)(out + (size_t)n2 * OUT_STRIDE + CONV_L);
            float4* d3 = (float4*)(out + (size_t)n3 * OUT_STRIDE + CONV_L);
            d0[lane] = a0;
            d1[lane] = a1;
            d2[lane] = a2;
            d3[lane] = a3;
            if (tail) {
                d0[64 + lane] = b0; d1[64 + lane] = b1;
                d2[64 + lane] = b2; d3[64 + lane] = b3;
            }
        }
        return;
    }

    const int cb   = (int)blockIdx.x - word_blocks;   // 0..511
    const int q    = cb & 3;                          // channel quarter
    const int wgrp = cb >> 2;                         // word group, 0..127

    const int g  = lane >> 3;   // word within the wave's 8
    const int l8 = lane & 7;    // owns channels q*64 + l8*8 .. +8

    // ---- hoisted global loads: X pass-0 row + bias (drain under staging) --
    int4 c0, c1, c2, c3;
    {
        const int n0 = wgrp * 128 + wv * 8 + g;
        const int4* xr = (const int4*)(X + n0 * L_CHARS);
        c0 = xr[0]; c1 = xr[1]; c2 = xr[2]; c3 = xr[3];
    }
    float bias[8];
    {
        const float4* bp = (const float4*)(conv_b + q * CH_Q + l8 * 8);
        float4 b0 = bp[0], b1 = bp[1];
        bias[0]=b0.x; bias[1]=b0.y; bias[2]=b0.z; bias[3]=b0.w;
        bias[4]=b1.x; bias[5]=b1.y; bias[6]=b1.z; bias[7]=b1.w;
    }

    // ---- stage the 48 KB slice (fully coalesced contiguous read) ----
    {
        const float4* src = (const float4*)(Th + q * SLICE_H);
        float4* dst = (float4*)Ts;
        #pragma unroll
        for (int i = 0; i < 12; ++i)
            dst[threadIdx.x + i * 256] = src[threadIdx.x + i * 256];
    }
    __syncthreads();

    #pragma unroll
    for (int pass = 0; pass < 4; ++pass) {
        int4 p0 = c0, p1 = c1, p2 = c2, p3 = c3;
        if (pass < 3) {
            const int n1 = wgrp * 128 + (pass + 1) * 32 + wv * 8 + g;
            const int4* xr = (const int4*)(X + n1 * L_CHARS);
            p0 = xr[0]; p1 = xr[1]; p2 = xr[2]; p3 = xr[3];
        }

        const int n = wgrp * 128 + pass * 32 + wv * 8 + g;
        int cs[16] = {c0.x, c0.y, c0.z, c0.w,
                      c1.x, c1.y, c1.z, c1.w,
                      c2.x, c2.y, c2.z, c2.w,
                      c3.x, c3.y, c3.z, c3.w};

        half8 a0 = (half8)(_Float16)0.f;
        half8 a1 = (half8)(_Float16)0.f;
        half8 m  = (half8)(_Float16)(-65504.f);

        #pragma unroll
        for (int j = 0; j < L_CHARS; ++j) {
            const _Float16* row = Ts + cs[j] * (KERNEL_K * CH_Q) + l8 * 8;
            half8 t0 = *(const half8*)(row);            // k=0
            half8 t1 = *(const half8*)(row + CH_Q);     // k=1
            half8 t2 = *(const half8*)(row + 2*CH_Q);   // k=2
            half8 yj = a0 + t2;          // y[j] complete
            m  = h8max(m, yj);
            a0 = a1 + t1;                // partial y[j+1]
            a1 = t0;                     // partial y[j+2]
        }
        m = h8max(m, a0);   // y[16]
        m = h8max(m, a1);   // y[17]

        float r[8];
        #pragma unroll
        for (int e = 0; e < 8; ++e)
            r[e] = fmaxf((float)m[e] + bias[e], 0.f);
        float4* dst = (float4*)(out + (size_t)n * OUT_STRIDE + q * CH_Q + l8 * 8);
        dst[0] = make_float4(r[0], r[1], r[2], r[3]);
        dst[1] = make_float4(r[4], r[5], r[6], r[7]);

        c0 = p0; c1 = p1; c2 = p2; c3 = p3;
    }
}

extern "C" void kernel_launch(void* const* d_in, const int* in_sizes, int n_in,
                              void* d_out, int out_size, void* d_ws, size_t ws_size,
                              hipStream_t stream) {
    const int*   X    = (const int*)d_in[0];
    const int*   Xw   = (const int*)d_in[1];
    const float* emb  = (const float*)d_in[2];
    const float* w    = (const float*)d_in[3];
    const float* b    = (const float*)d_in[4];
    const float* we   = (const float*)d_in[5];
    float* out = (float*)d_out;

    // ws layout: Th (fp16, 196608 B)
    _Float16* Th = (_Float16*)d_ws;

    build_table_fused<<<CONV_L, 384, 0, stream>>>(emb, w, Th);

    const int WB = 256;    // word-gather blocks
    const int CB = 512;    // char blocks: 4 quarters x 128 word-groups
    main_kernel<<<WB + CB, 256, 0, stream>>>(X, Xw, Th, b, we, out, WB);
}